// Round 1
// baseline (297.478 us; speedup 1.0000x reference)
//
#include <hip/hip_runtime.h>
#include <stdint.h>

#define NLAYERS 3
#define NQ 8
#define DIM 256          // 2^NQ
#define HALF 128         // measured output amplitudes
#define BATCH 131072

typedef float  f32x4  __attribute__((ext_vector_type(4)));
typedef __bf16 bf16x8 __attribute__((ext_vector_type(8)));

__device__ __forceinline__ unsigned short f2bf(float f){
    union { float f; uint32_t u; } v; v.f = f;
    uint32_t u = v.u;
    u += 0x7fffu + ((u >> 16) & 1u);   // round-to-nearest-even
    return (unsigned short)(u >> 16);
}

__device__ __forceinline__ float2 cmul(float2 a, float2 b){
    return make_float2(a.x*b.x - a.y*b.y, a.x*b.y + a.y*b.x);
}

// async 16B global -> LDS (lane dest = uniform base + lane*16)
__device__ __forceinline__ void gload_lds16(void* lds, const void* g){
    __builtin_amdgcn_global_load_lds(
        (const __attribute__((address_space(1))) unsigned int*)g,
        (__attribute__((address_space(3))) unsigned int*)lds,
        16, 0, 0);
}

// ---------------------------------------------------------------------------
// Kernel 1: simulate circuit on basis state e_j (block j) and emit the
// 128x256 complex matrix W as two bf16 planes (Wre, Wim), stored PRE-SWIZZLED
// (granule g of row n lands at slot g ^ (n&7)) so kernel 2 can DMA the image
// linearly into LDS and read conflict-free with ds_read_b128.
// Image: ushort[65536] = 128 KB. [0,32768): Wre, [32768,65536): Wim.
// ---------------------------------------------------------------------------
__global__ __launch_bounds__(256) void build_w_kernel(const float* __restrict__ params,
                                                      unsigned short* __restrict__ W){
    __shared__ float2 st[2][DIM];
    __shared__ float2 gm[NLAYERS*NQ][4];   // U0a,U0b,U1a,U1b per gate
    const int j = blockIdx.x;
    const int i = threadIdx.x;

    if (i < NLAYERS*NQ){
        const float* pp = params + i*3;
        float hx = 0.5f*pp[0], hy = 0.5f*pp[1], hz = 0.5f*pp[2];
        float cx = cosf(hx), sx = sinf(hx);
        float cy = cosf(hy), sy = sinf(hy);
        float cz = cosf(hz), sz = sinf(hz);
        float2 ezm = make_float2(cz, -sz), ezp = make_float2(cz, sz);
        float2 m00 = make_float2( cy*cx,  sy*sx);
        float2 m01 = make_float2(-sy*cx, -cy*sx);
        float2 m10 = make_float2( sy*cx, -cy*sx);
        float2 m11 = make_float2( cy*cx, -sy*sx);
        gm[i][0] = cmul(ezm, m00);
        gm[i][1] = cmul(ezm, m01);
        gm[i][2] = cmul(ezp, m10);
        gm[i][3] = cmul(ezp, m11);
    }

    // composed CNOT-ring permutation (params-independent, same all layers)
    int psrc = i;
    #pragma unroll
    for (int q = NQ-1; q >= 0; --q){
        int c  = 7 - q;
        int tb = 7 - ((q + 1) & 7);
        psrc = ((psrc >> c) & 1) ? (psrc ^ (1 << tb)) : psrc;
    }

    int cur = 0;
    st[0][i] = make_float2(i == j ? 1.0f : 0.0f, 0.0f);
    __syncthreads();

    for (int l = 0; l < NLAYERS; ++l){
        for (int q = 0; q < NQ; ++q){
            float2 U0a = gm[l*NQ+q][0], U0b = gm[l*NQ+q][1];
            float2 U1a = gm[l*NQ+q][2], U1b = gm[l*NQ+q][3];
            int p  = 7 - q;
            int bs = (i >> p) & 1;
            int i0 = i & ~(1 << p), i1 = i | (1 << p);
            float2 a0 = st[cur][i0], a1 = st[cur][i1];
            float2 ua = bs ? U1a : U0a;
            float2 ub = bs ? U1b : U0b;
            float2 r;
            r.x = ua.x*a0.x - ua.y*a0.y + ub.x*a1.x - ub.y*a1.y;
            r.y = ua.x*a0.y + ua.y*a0.x + ub.x*a1.y + ub.y*a1.x;
            st[cur ^ 1][i] = r;
            cur ^= 1;
            __syncthreads();
        }
        // fused CNOT ring
        float2 r = st[cur][psrc];
        st[cur ^ 1][i] = r;
        cur ^= 1;
        __syncthreads();
    }

    // column j of W: thread i<128 -> Wre[i][j], thread i>=128 -> Wim[i-128][j]
    const int m = i & 127;
    float2 a = st[cur][m];
    // swizzled offset (ushort units): row m (512 B = 32 granules of 16 B)
    const uint32_t off = (uint32_t)m*256u
                       + ((((uint32_t)j >> 3) ^ ((uint32_t)m & 7u)) << 3)
                       + ((uint32_t)j & 7u);
    if (i < 128) W[off]          = f2bf(a.x);
    else         W[32768u + off] = f2bf(a.y);
}

// ---------------------------------------------------------------------------
// Kernel 2: out[m] = sum_j |sum_k W[j][k]*(sr[m][k] + i si[m][k])|^2
// 256 blocks x 1024 threads (16 waves, 1 block/CU). B = Wre/Wim resident in
// 128 KB LDS (loaded once, ONE barrier). Each wave owns 32 rows (2 tiles of
// 16) and streams A fragments directly global->register with 1-kstep
// prefetch. 4 MFMAs per (kstep, j-frag):
//   Re += a_r*b_r + (-a_i)*b_i ;  Im += a_r*b_i + a_i*b_r
// No barriers / vmcnt(0) drains in the main loop.
// ---------------------------------------------------------------------------
__global__ __launch_bounds__(1024) void qform2_kernel(const float* __restrict__ sr,
                                                      const float* __restrict__ si,
                                                      const unsigned short* __restrict__ W,
                                                      float* __restrict__ out){
    __shared__ unsigned short Bs[65536];   // 128 KB: [0,32768) Wre, [32768,65536) Wim

    const int tid  = threadIdx.x;
    const int lane = tid & 63;
    const int w    = tid >> 6;        // 0..15
    const int l15  = lane & 15;
    const int quad = lane >> 4;       // 0..3

    // ---- stage W image linearly: 128 chunks x 1 KB (image is pre-swizzled)
    #pragma unroll
    for (int r = 0; r < 8; ++r){
        const int c = w*8 + r;                       // 0..127
        gload_lds16(&Bs[c*512], W + (size_t)c*512 + lane*8);
    }
    __syncthreads();

    const size_t row0 = (size_t)blockIdx.x * 512 + (size_t)w * 32;

    #pragma unroll 1
    for (int t = 0; t < 2; ++t){
        const float* ar = sr + (row0 + (size_t)(t*16 + l15)) * DIM;
        const float* ai = si + (row0 + (size_t)(t*16 + l15)) * DIM;

        f32x4 accR[8], accI[8];
        const f32x4 z = {0.0f, 0.0f, 0.0f, 0.0f};
        #pragma unroll
        for (int jf = 0; jf < 8; ++jf){ accR[jf] = z; accI[jf] = z; }

        // kstep 0 loads (32 B contiguous per lane, per array)
        float4 r0 = *(const float4*)(ar + quad*8);
        float4 r1 = *(const float4*)(ar + quad*8 + 4);
        float4 q0 = *(const float4*)(ai + quad*8);
        float4 q1 = *(const float4*)(ai + quad*8 + 4);

        #pragma unroll 1
        for (int ks = 0; ks < 8; ++ks){
            // convert current kstep fp32 -> bf16 fragments (truncation, as before)
            union { float4 v; uint32_t u[4]; } ha, hb;
            union { uint32_t u[4]; bf16x8 f; } pr, pi, pn;
            ha.v = r0; hb.v = r1;
            pr.u[0] = __builtin_amdgcn_perm(ha.u[1], ha.u[0], 0x07060302);
            pr.u[1] = __builtin_amdgcn_perm(ha.u[3], ha.u[2], 0x07060302);
            pr.u[2] = __builtin_amdgcn_perm(hb.u[1], hb.u[0], 0x07060302);
            pr.u[3] = __builtin_amdgcn_perm(hb.u[3], hb.u[2], 0x07060302);
            ha.v = q0; hb.v = q1;
            pi.u[0] = __builtin_amdgcn_perm(ha.u[1], ha.u[0], 0x07060302);
            pi.u[1] = __builtin_amdgcn_perm(ha.u[3], ha.u[2], 0x07060302);
            pi.u[2] = __builtin_amdgcn_perm(hb.u[1], hb.u[0], 0x07060302);
            pi.u[3] = __builtin_amdgcn_perm(hb.u[3], hb.u[2], 0x07060302);
            pn.u[0] = pi.u[0] ^ 0x80008000u;
            pn.u[1] = pi.u[1] ^ 0x80008000u;
            pn.u[2] = pi.u[2] ^ 0x80008000u;
            pn.u[3] = pi.u[3] ^ 0x80008000u;
            const bf16x8 fr = pr.f;        // bf16(sr)
            const bf16x8 fi = pi.f;        // bf16(si)
            const bf16x8 fn = pn.f;        // -bf16(si)

            // prefetch next kstep (last iter re-reads kstep 7: L1 hit, harmless)
            const int nk = (ks < 7) ? (ks + 1) : 7;
            r0 = *(const float4*)(ar + nk*32 + quad*8);
            r1 = *(const float4*)(ar + nk*32 + quad*8 + 4);
            q0 = *(const float4*)(ai + nk*32 + quad*8);
            q1 = *(const float4*)(ai + nk*32 + quad*8 + 4);

            // swizzled LDS base for this kstep (ushort units); n&7 == l15&7
            const int ub = l15*256 + (((ks*4 + quad) ^ (l15 & 7)) << 3);

            #pragma unroll
            for (int jf = 0; jf < 8; ++jf){
                const bf16x8 br = *(const bf16x8*)&Bs[ub + jf*4096];           // Wre
                const bf16x8 bi = *(const bf16x8*)&Bs[32768 + ub + jf*4096];   // Wim
                accR[jf] = __builtin_amdgcn_mfma_f32_16x16x32_bf16(fr, br, accR[jf], 0, 0, 0);
                accR[jf] = __builtin_amdgcn_mfma_f32_16x16x32_bf16(fn, bi, accR[jf], 0, 0, 0);
                accI[jf] = __builtin_amdgcn_mfma_f32_16x16x32_bf16(fr, bi, accI[jf], 0, 0, 0);
                accI[jf] = __builtin_amdgcn_mfma_f32_16x16x32_bf16(fi, br, accI[jf], 0, 0, 0);
            }
        }

        // epilogue: C/D layout row = quad*4 + r, col = jf*16 + l15.
        // out[row] = sum over all 128 j of Re^2 + Im^2
        float s[4];
        #pragma unroll
        for (int r = 0; r < 4; ++r){
            float tt = 0.0f;
            #pragma unroll
            for (int jf = 0; jf < 8; ++jf){
                const float vr = accR[jf][r];
                const float vi = accI[jf][r];
                tt += vr*vr + vi*vi;
            }
            tt += __shfl_xor(tt, 1);
            tt += __shfl_xor(tt, 2);
            tt += __shfl_xor(tt, 4);
            tt += __shfl_xor(tt, 8);
            s[r] = tt;
        }
        if (l15 == 0){
            float4 o; o.x = s[0]; o.y = s[1]; o.z = s[2]; o.w = s[3];
            *(float4*)(out + row0 + t*16 + quad*4) = o;
        }
    }
}

extern "C" void kernel_launch(void* const* d_in, const int* in_sizes, int n_in,
                              void* d_out, int out_size, void* d_ws, size_t ws_size,
                              hipStream_t stream){
    const float* params = (const float*)d_in[0];
    const float* sr     = (const float*)d_in[1];
    const float* si     = (const float*)d_in[2];
    unsigned short* Wimg = (unsigned short*)d_ws;   // 128 KB image
    float* out          = (float*)d_out;

    build_w_kernel<<<dim3(DIM), dim3(256), 0, stream>>>(params, Wimg);
    qform2_kernel<<<dim3(256), dim3(1024), 0, stream>>>(sr, si, Wimg, out);
}